// Round 2
// baseline (1069.104 us; speedup 1.0000x reference)
//
#include <hip/hip_runtime.h>
#include <cstdint>

typedef __bf16 bf16_t;
typedef __bf16 bf16x8 __attribute__((ext_vector_type(8)));
typedef float f32x4 __attribute__((ext_vector_type(4)));

#define AS1 __attribute__((address_space(1)))
#define AS3 __attribute__((address_space(3)))

__device__ __forceinline__ void gload_lds16(const bf16_t* g, bf16_t* l) {
    __builtin_amdgcn_global_load_lds((const AS1 void*)g, (AS3 void*)l, 16, 0, 0);
}
__device__ __forceinline__ f32x4 mfma_bf16(bf16x8 a, bf16x8 b, f32x4 c) {
    return __builtin_amdgcn_mfma_f32_16x16x32_bf16(a, b, c, 0, 0, 0);
}

// ---------------------------------------------------------------------------
// 256x256-tile GEMM, C[row,col] = sum_k A[row,k]*B[col,k] (+bias).
// 512 threads = 8 waves (2 M x 4 N), per-wave output 128x64 (8x4 16x16 frags).
// K processed in 32-wide tiles through a 4-deep LDS ring (4 x 32KB = 128KB):
// tile j+3 staged (global_load_lds, pre-swizzled source) while computing j.
// Counted s_waitcnt vmcnt(8) at tile boundaries -- loads for j+2/j+3 stay in
// flight across raw s_barrier (no __syncthreads -> no vmcnt(0) drain).
// LDS 16B-slot swizzle phys = slot ^ ((row>>1)&3): conflict-free ds_read_b128
// (verified 0 bank conflicts in round 1 with the same involution).
// SPLIT: logical K' = 3K; tile jt = (chunk=jt/3, term=jt%3) with
//   term 0: Ah*Bh, 1: Ah*Bl, 2: Al*Bh  (fp32-split product, 3 passes).
// BIAS: 0=none, 1=+bias[col], 2=+bias[row].  OUTMODE: 0 fp32; 1 bf16;
// 2 split (hi->C0, lo->C1).
// ---------------------------------------------------------------------------
template <bool SPLIT, int BIAS, int OUTMODE>
__global__ __launch_bounds__(512, 2) void gemm256(
    const bf16_t* __restrict__ Ah, const bf16_t* __restrict__ Al, long long strideA, int lda,
    const bf16_t* __restrict__ Bh, const bf16_t* __restrict__ Bl, long long strideB, int ldb,
    void* __restrict__ C0, void* __restrict__ C1, long long strideC, int ldc,
    const float* __restrict__ bias, int K)
{
    __shared__ bf16_t lds[4 * 16384];   // 4 ring buffers: [A 256x32 | B 256x32] each

    const int bz = blockIdx.z;
    const int rowBase = blockIdx.y * 256;
    const int colBase = blockIdx.x * 256;
    const bf16_t* AhB = Ah + (long long)bz * strideA;
    const bf16_t* BhB = Bh + (long long)bz * strideB;
    const bf16_t* AlB = SPLIT ? Al + (long long)bz * strideA : nullptr;
    const bf16_t* BlB = SPLIT ? Bl + (long long)bz * strideB : nullptr;

    const int t = threadIdx.x;
    const int lane = t & 63;
    const int w = t >> 6;
    const int wm = w >> 2;   // 0..1 -> row offset wm*128
    const int wn = w & 3;    // 0..3 -> col offset wn*64

    // --- staging precompute (per thread, tile-invariant) ---
    // chunk c = li*512 + t; li 0/1 -> A halves, 2/3 -> B halves.
    // row r = c>>2 (mod 128 per half), phys slot p = t&3,
    // logical slot sl = p ^ ((r>>1)&3)  (same for r and r+128).
    const int r0 = t >> 2;
    const int sl8 = ((t & 3) ^ ((r0 >> 1) & 3)) * 8;
    const long long aoff0 = (long long)(rowBase + r0) * lda + sl8;
    const long long aoff1 = (long long)(rowBase + r0 + 128) * lda + sl8;
    const long long boff0 = (long long)(colBase + r0) * ldb + sl8;
    const long long boff1 = (long long)(colBase + r0 + 128) * ldb + sl8;

    const int NT = SPLIT ? (K >> 5) * 3 : (K >> 5);

    auto tsrc = [&](int jt, const bf16_t*& sA, const bf16_t*& sB, long long& k0) {
        if (SPLIT) {
            const int chunk = jt / 3;
            const int term = jt - chunk * 3;
            k0 = (long long)chunk * 32;
            sA = (term == 2) ? AlB : AhB;
            sB = (term == 1) ? BlB : BhB;
        } else {
            k0 = (long long)jt * 32;
            sA = AhB; sB = BhB;
        }
    };

    f32x4 acc[8][4] = {};

    // --- prologue: stage tiles 0..2 (12 gloads/wave) ---
    for (int jt = 0; jt < 3; ++jt) {
        const bf16_t *sA, *sB; long long k0;
        tsrc(jt, sA, sB, k0);
        bf16_t* db = lds + jt * 16384;
        gload_lds16(sA + aoff0 + k0, db + t * 8);
        gload_lds16(sA + aoff1 + k0, db + 4096 + t * 8);
        gload_lds16(sB + boff0 + k0, db + 8192 + t * 8);
        gload_lds16(sB + boff1 + k0, db + 12288 + t * 8);
    }
    asm volatile("s_waitcnt vmcnt(8)" ::: "memory");   // tile 0 landed; 1,2 in flight
    __builtin_amdgcn_s_barrier();

    const int fr = lane & 15;
    const int kqs = ((lane >> 4) ^ ((lane >> 1) & 3)) * 8;   // swizzled k-chunk

    for (int j = 0; j < NT; ++j) {
        const bf16_t* bufA = lds + (j & 3) * 16384;
        const bf16_t* bufB = bufA + 8192;
        const int jt = j + 3;
        const bool doStage = jt < NT;
        const bf16_t *sA = nullptr, *sB = nullptr; long long k0 = 0;
        if (doStage) tsrc(jt, sA, sB, k0);
        bf16_t* db = lds + (jt & 3) * 16384;

        bf16x8 a[4], b[4];
        // ---- phase 0: C rows wm*128+[0,64), all 4 n-frags ----
#pragma unroll
        for (int mi = 0; mi < 4; mi++)
            a[mi] = *(const bf16x8*)&bufA[(wm * 128 + mi * 16 + fr) * 32 + kqs];
#pragma unroll
        for (int ni = 0; ni < 4; ni++)
            b[ni] = *(const bf16x8*)&bufB[(wn * 64 + ni * 16 + fr) * 32 + kqs];
        if (doStage) {
            gload_lds16(sA + aoff0 + k0, db + t * 8);
            gload_lds16(sA + aoff1 + k0, db + 4096 + t * 8);
        }
        asm volatile("" ::: "memory");
        __builtin_amdgcn_s_barrier();
        __builtin_amdgcn_s_setprio(1);
#pragma unroll
        for (int mi = 0; mi < 4; mi++)
#pragma unroll
            for (int ni = 0; ni < 4; ni++)
                acc[mi][ni] = mfma_bf16(a[mi], b[ni], acc[mi][ni]);
        __builtin_amdgcn_s_setprio(0);
        asm volatile("" ::: "memory");
        __builtin_amdgcn_s_barrier();
        // ---- phase 1: C rows wm*128+[64,128), reuse b[] ----
#pragma unroll
        for (int mi = 0; mi < 4; mi++)
            a[mi] = *(const bf16x8*)&bufA[(wm * 128 + (mi + 4) * 16 + fr) * 32 + kqs];
        if (doStage) {
            gload_lds16(sB + boff0 + k0, db + 8192 + t * 8);
            gload_lds16(sB + boff1 + k0, db + 12288 + t * 8);
        }
        asm volatile("" ::: "memory");
        __builtin_amdgcn_s_barrier();
        __builtin_amdgcn_s_setprio(1);
#pragma unroll
        for (int mi = 0; mi < 4; mi++)
#pragma unroll
            for (int ni = 0; ni < 4; ni++)
                acc[mi + 4][ni] = mfma_bf16(a[mi], b[ni], acc[mi + 4][ni]);
        __builtin_amdgcn_s_setprio(0);
        // ---- tile boundary: counted wait (tile j+1 landed; j+2,j+3 fly) ----
        if (j + 1 < NT) {
            if (j < NT - 3)       asm volatile("s_waitcnt vmcnt(8)" ::: "memory");
            else if (j == NT - 3) asm volatile("s_waitcnt vmcnt(4)" ::: "memory");
            else                  asm volatile("s_waitcnt vmcnt(0)" ::: "memory");
            __builtin_amdgcn_s_barrier();
        }
    }

    // epilogue: C/D layout col = lane&15, row = (lane>>4)*4 + reg
    const int fc = lane & 15;
    const int fr4 = (lane >> 4) * 4;
#pragma unroll
    for (int mi = 0; mi < 8; mi++)
#pragma unroll
        for (int ni = 0; ni < 4; ni++)
#pragma unroll
            for (int rg = 0; rg < 4; rg++) {
                const int row = rowBase + wm * 128 + mi * 16 + fr4 + rg;
                const int col = colBase + wn * 64 + ni * 16 + fc;
                float v = acc[mi][ni][rg];
                if (BIAS == 1) v += bias[col];
                else if (BIAS == 2) v += bias[row];
                const long long off = (long long)bz * strideC + (long long)row * ldc + col;
                if (OUTMODE == 0) {
                    ((float*)C0)[off] = v;
                } else if (OUTMODE == 1) {
                    ((bf16_t*)C0)[off] = (bf16_t)v;
                } else {
                    const bf16_t h = (bf16_t)v;
                    ((bf16_t*)C0)[off] = h;
                    ((bf16_t*)C1)[off] = (bf16_t)(v - (float)h);
                }
            }
}

// fp32 -> (hi, lo) bf16 split; n multiple of 1024; grid = n/1024 blocks of 256.
__global__ __launch_bounds__(256) void split_f32(const float* __restrict__ x,
                                                 bf16_t* __restrict__ h,
                                                 bf16_t* __restrict__ l)
{
    const long long i = ((long long)blockIdx.x * 256 + threadIdx.x) * 4;
    const float4 v = *(const float4*)&x[i];
    bf16_t hh[4], ll[4];
    const float vv[4] = {v.x, v.y, v.z, v.w};
#pragma unroll
    for (int j = 0; j < 4; j++) {
        hh[j] = (bf16_t)vv[j];
        ll[j] = (bf16_t)(vv[j] - (float)hh[j]);
    }
    *(short4*)&h[i] = *(short4*)hh;
    *(short4*)&l[i] = *(short4*)ll;
}

// fp32 -> bf16 cast; n multiple of 1024; grid = n/1024.
__global__ __launch_bounds__(256) void cast_f32(const float* __restrict__ x,
                                                bf16_t* __restrict__ y)
{
    const long long i = ((long long)blockIdx.x * 256 + threadIdx.x) * 4;
    const float4 v = *(const float4*)&x[i];
    bf16_t hh[4] = {(bf16_t)v.x, (bf16_t)v.y, (bf16_t)v.z, (bf16_t)v.w};
    *(short4*)&y[i] = *(short4*)hh;
}

// Row softmax with mask; S fp32 [rows][2048] -> P bf16 [rows][2048].
// mask row = n0 + (r & 2047).
__global__ __launch_bounds__(256) void softmax_rows(const float* __restrict__ S,
                                                    bf16_t* __restrict__ P,
                                                    const int* __restrict__ mask,
                                                    int n0)
{
    __shared__ float red[4];
    const long long r = blockIdx.x;
    const float* row = S + r * 2048;
    const int* mrow = mask + (long long)(n0 + (int)(r & 2047)) * 2048;
    const int t = threadIdx.x;

    float v[8];
#pragma unroll
    for (int i = 0; i < 8; i++) {
        const int j = i * 256 + t;
        v[i] = (mrow[j] != 0) ? row[j] : -1000000000.0f;
    }
    float m = v[0];
#pragma unroll
    for (int i = 1; i < 8; i++) m = fmaxf(m, v[i]);
#pragma unroll
    for (int off = 32; off; off >>= 1) m = fmaxf(m, __shfl_xor(m, off));
    if ((t & 63) == 0) red[t >> 6] = m;
    __syncthreads();
    const float rowmax = fmaxf(fmaxf(red[0], red[1]), fmaxf(red[2], red[3]));
    __syncthreads();

    float sum = 0.0f;
    float e[8];
#pragma unroll
    for (int i = 0; i < 8; i++) { e[i] = __expf(v[i] - rowmax); sum += e[i]; }
#pragma unroll
    for (int off = 32; off; off >>= 1) sum += __shfl_xor(sum, off);
    if ((t & 63) == 0) red[t >> 6] = sum;
    __syncthreads();
    const float inv = 1.0f / (red[0] + red[1] + red[2] + red[3]);

    bf16_t* prow = P + r * 2048;
#pragma unroll
    for (int i = 0; i < 8; i++) prow[i * 256 + t] = (bf16_t)(e[i] * inv);
}

extern "C" void kernel_launch(void* const* d_in, const int* in_sizes, int n_in,
                              void* d_out, int out_size, void* d_ws, size_t ws_size,
                              hipStream_t stream) {
    constexpr int Bb = 8, N = 2048, M = 2048, D = 1024;
    constexpr long long MB = 1LL << 20;

    const float* querys = (const float*)d_in[0];
    const float* keys   = (const float*)d_in[1];
    const float* values = (const float*)d_in[2];
    const int*   mask   = (const int*)d_in[3];
    const float* Wq = (const float*)d_in[4];
    const float* bq = (const float*)d_in[5];
    const float* Wk = (const float*)d_in[6];
    const float* bk = (const float*)d_in[7];
    const float* Wv = (const float*)d_in[8];
    const float* bv = (const float*)d_in[9];
    float* out = (float*)d_out;

    // ---- adaptive plan ----
    // Batched: need(CB) = 10 MiB weights + CB * 52 MiB
    //   (X 8 + Q 8 + K 8 + VT 4 + S 16 + P 8 per batch, MiB)
    // Fallback (tiny ws): CB=1, n-chunked attention with NCH in {512, 256}.
    const long long w = (long long)ws_size;
    auto needB = [&](long long cb) { return 10 * MB + cb * 52 * MB; };
    int CB = 0;
    if      (w >= needB(8)) CB = 8;
    else if (w >= needB(4)) CB = 4;
    else if (w >= needB(2)) CB = 2;
    else if (w >= needB(1)) CB = 1;
    const bool batched = (CB != 0);
    int NCH = N;
    if (!batched) {
        CB = 1;
        NCH = (w >= 38 * MB + 512 * 2048 * 6) ? 512 : 256;
    }

    char* ws = (char*)d_ws;
    long long o = 0;
    auto carve = [&](long long bytes) { char* p = ws + o; o += bytes; return p; };
    bf16_t* WqH = (bf16_t*)carve(2 * MB);
    bf16_t* WqL = (bf16_t*)carve(2 * MB);
    bf16_t* WkH = (bf16_t*)carve(2 * MB);
    bf16_t* WkL = (bf16_t*)carve(2 * MB);
    bf16_t* WvB = (bf16_t*)carve(2 * MB);
    bf16_t* XH  = (bf16_t*)carve((long long)CB * 4 * MB);  // also reused as V staging
    bf16_t* XL  = (bf16_t*)carve((long long)CB * 4 * MB);
    bf16_t* QH  = (bf16_t*)carve((long long)CB * 4 * MB);
    bf16_t* QL  = (bf16_t*)carve((long long)CB * 4 * MB);
    bf16_t* KH  = (bf16_t*)carve((long long)CB * 4 * MB);
    bf16_t* KL  = (bf16_t*)carve((long long)CB * 4 * MB);
    bf16_t* VT  = (bf16_t*)carve((long long)CB * 4 * MB);  // [CB][D][M]
    float*  S   = (float*)carve(batched ? (long long)CB * N * M * 4 : (long long)NCH * 2048 * 4);
    bf16_t* P   = (bf16_t*)carve(batched ? (long long)CB * N * M * 2 : (long long)NCH * 2048 * 2);

    dim3 blk(256), blkG(512);
    const long long grpElems = (long long)CB * N * D;

    // weight conversions (once)
    split_f32<<<dim3((D * D) / 1024), blk, 0, stream>>>(Wq, WqH, WqL);
    split_f32<<<dim3((D * D) / 1024), blk, 0, stream>>>(Wk, WkH, WkL);
    cast_f32<<<dim3((D * D) / 1024), blk, 0, stream>>>(Wv, WvB);

    for (int b0 = 0; b0 < Bb; b0 += CB) {
        const long long xoff = (long long)b0 * N * D;
        // q = xq @ Wq^T + bq -> split (rows = CB*N)
        split_f32<<<dim3(grpElems / 1024), blk, 0, stream>>>(querys + xoff, XH, XL);
        gemm256<true, 1, 2><<<dim3(D / 256, CB * N / 256, 1), blkG, 0, stream>>>(
            XH, XL, 0, D, WqH, WqL, 0, D, QH, QL, 0, D, bq, D);
        // k = xk @ Wk^T + bk -> split
        split_f32<<<dim3(grpElems / 1024), blk, 0, stream>>>(keys + xoff, XH, XL);
        gemm256<true, 1, 2><<<dim3(D / 256, CB * M / 256, 1), blkG, 0, stream>>>(
            XH, XL, 0, D, WkH, WkL, 0, D, KH, KL, 0, D, bk, D);
        // vT[z][d][m] = sum_e Wv[d][e]*xv[z][m][e] + bv[d]  (XH = V staging)
        cast_f32<<<dim3(grpElems / 1024), blk, 0, stream>>>(values + xoff, XH);
        gemm256<false, 2, 1><<<dim3(M / 256, D / 256, CB), blkG, 0, stream>>>(
            WvB, nullptr, 0, D, XH, nullptr, (long long)M * D, D,
            VT, nullptr, (long long)D * M, M, bv, D);

        if (batched) {
            // S[z][n][m] = q[z][n] . k[z][m]  (fp32, split)
            gemm256<true, 0, 0><<<dim3(M / 256, N / 256, CB), blkG, 0, stream>>>(
                QH, QL, (long long)N * D, D,
                KH, KL, (long long)M * D, D,
                S, nullptr, (long long)N * M, M, nullptr, D);
            softmax_rows<<<dim3(CB * N), blk, 0, stream>>>(S, P, mask, 0);
            // out[z][n][d] = sum_m P[z][n][m] * vT[z][d][m]
            gemm256<false, 0, 0><<<dim3(D / 256, N / 256, CB), blkG, 0, stream>>>(
                P, nullptr, (long long)N * M, M,
                VT, nullptr, (long long)D * M, M,
                out + xoff, nullptr, (long long)N * D, D, nullptr, M);
        } else {
            for (int z = 0; z < CB; z++) {
                for (int n0 = 0; n0 < N; n0 += NCH) {
                    gemm256<true, 0, 0><<<dim3(M / 256, NCH / 256, 1), blkG, 0, stream>>>(
                        QH + ((long long)z * N + n0) * D, QL + ((long long)z * N + n0) * D, 0, D,
                        KH + (long long)z * M * D, KL + (long long)z * M * D, 0, D,
                        S, nullptr, 0, M, nullptr, D);
                    softmax_rows<<<dim3(NCH), blk, 0, stream>>>(S, P, mask, n0);
                    gemm256<false, 0, 0><<<dim3(D / 256, NCH / 256, 1), blkG, 0, stream>>>(
                        P, nullptr, 0, M, VT + (long long)z * D * M, nullptr, 0, M,
                        out + ((long long)(b0 + z) * N + n0) * D, nullptr, 0, D, nullptr, M);
                }
            }
        }
    }
    (void)in_sizes; (void)n_in; (void)out_size;
}

// Round 3
// 1004.915 us; speedup vs baseline: 1.0639x; 1.0639x over previous
//
#include <hip/hip_runtime.h>
#include <cstdint>

typedef __bf16 bf16_t;
typedef __bf16 bf16x8 __attribute__((ext_vector_type(8)));
typedef float f32x4 __attribute__((ext_vector_type(4)));

#define AS1 __attribute__((address_space(1)))
#define AS3 __attribute__((address_space(3)))

__device__ __forceinline__ void gload_lds16(const bf16_t* g, bf16_t* l) {
    __builtin_amdgcn_global_load_lds((const AS1 void*)g, (AS3 void*)l, 16, 0, 0);
}
__device__ __forceinline__ f32x4 mfma_bf16(bf16x8 a, bf16x8 b, f32x4 c) {
    return __builtin_amdgcn_mfma_f32_16x16x32_bf16(a, b, c, 0, 0, 0);
}

// ---------------------------------------------------------------------------
// 256x256-tile GEMM, C[row,col] = sum_k A[row,k]*B[col,k] (+bias).
// 512 threads = 8 waves (2 M x 4 N), per-wave output 128x64 (8x4 16x16 frags).
// K in 32-wide tiles through a 4-deep LDS ring (4 x 32KB = 128KB), tile j+3
// staged while computing tile j.  ONE sync point per tile: counted
// s_waitcnt vmcnt(8) + raw s_barrier (loads for j+2/j+3 stay in flight across
// the barrier; never drained to 0 in the main loop).  Per tile: 12 ds_read_b128
// -> 32-MFMA cluster (compiler interleaves via its own lgkmcnt scheduling).
// LDS 16B-slot swizzle phys = slot ^ ((row>>1)&3) on BOTH sides (pre-swizzled
// global source + swizzled ds_read): 0 bank conflicts (verified rounds 1-2).
// XCD-aware bijective block swizzle (identity unless nwg%8==0) for L2 locality.
// SPLIT: logical K' = 3K; tile jt = (chunk=jt/3, term=jt%3) with
//   term 0: Ah*Bh, 1: Ah*Bl, 2: Al*Bh.
// BIAS: 0=none, 1=+bias[col], 2=+bias[row].  OUTMODE: 0 fp32; 1 bf16;
// 2 split (hi->C0, lo->C1).
// ---------------------------------------------------------------------------
template <bool SPLIT, int BIAS, int OUTMODE>
__global__ __launch_bounds__(512, 2) void gemm256(
    const bf16_t* __restrict__ Ah, const bf16_t* __restrict__ Al, long long strideA, int lda,
    const bf16_t* __restrict__ Bh, const bf16_t* __restrict__ Bl, long long strideB, int ldb,
    void* __restrict__ C0, void* __restrict__ C1, long long strideC, int ldc,
    const float* __restrict__ bias, int K)
{
    __shared__ bf16_t lds[4 * 16384];   // 4 ring buffers: [A 256x32 | B 256x32]

    // XCD-aware swizzle: consecutive-dispatch blocks (same XCD) get contiguous
    // tile chunks -> neighbor tiles sharing A/B panels hit the same L2.
    int bx = blockIdx.x, by = blockIdx.y, bz = blockIdx.z;
    {
        const int gx = gridDim.x, gy = gridDim.y, gz = gridDim.z;
        const int n = gx * gy * gz;
        if ((n & 7) == 0) {
            int lin = bx + gx * (by + gy * bz);
            lin = (lin & 7) * (n >> 3) + (lin >> 3);   // bijective since n%8==0
            bx = lin % gx; lin /= gx;
            by = lin % gy; bz = lin / gy;
        }
    }

    const int rowBase = by * 256;
    const int colBase = bx * 256;
    const bf16_t* AhB = Ah + (long long)bz * strideA;
    const bf16_t* BhB = Bh + (long long)bz * strideB;
    const bf16_t* AlB = SPLIT ? Al + (long long)bz * strideA : nullptr;
    const bf16_t* BlB = SPLIT ? Bl + (long long)bz * strideB : nullptr;

    const int t = threadIdx.x;
    const int lane = t & 63;
    const int w = t >> 6;
    const int wm = w >> 2;   // 0..1 -> row offset wm*128
    const int wn = w & 3;    // 0..3 -> col offset wn*64

    // staging: thread t handles rows r0, r0+128 of A and B at 16B slot (t&3);
    // pre-swizzled source slot sl = (t&3) ^ ((r0>>1)&3)  (same for r0+128).
    const int r0 = t >> 2;
    const int sl8 = ((t & 3) ^ ((r0 >> 1) & 3)) * 8;
    const long long aoff0 = (long long)(rowBase + r0) * lda + sl8;
    const long long aoff1 = (long long)(rowBase + r0 + 128) * lda + sl8;
    const long long boff0 = (long long)(colBase + r0) * ldb + sl8;
    const long long boff1 = (long long)(colBase + r0 + 128) * ldb + sl8;

    const int NT = SPLIT ? (K >> 5) * 3 : (K >> 5);

    auto tsrc = [&](int jt, const bf16_t*& sA, const bf16_t*& sB, long long& k0) {
        if (SPLIT) {
            const int chunk = jt / 3;
            const int term = jt - chunk * 3;
            k0 = (long long)chunk * 32;
            sA = (term == 2) ? AlB : AhB;
            sB = (term == 1) ? BlB : BhB;
        } else {
            k0 = (long long)jt * 32;
            sA = AhB; sB = BhB;
        }
    };

    f32x4 acc[8][4] = {};

    // prologue: stage tiles 0..2 (12 gloads/thread group)
    for (int jt = 0; jt < 3; ++jt) {
        const bf16_t *sA, *sB; long long k0;
        tsrc(jt, sA, sB, k0);
        bf16_t* db = lds + jt * 16384;
        gload_lds16(sA + aoff0 + k0, db + t * 8);
        gload_lds16(sA + aoff1 + k0, db + 4096 + t * 8);
        gload_lds16(sB + boff0 + k0, db + 8192 + t * 8);
        gload_lds16(sB + boff1 + k0, db + 12288 + t * 8);
    }
    asm volatile("s_waitcnt vmcnt(8)" ::: "memory");   // tile 0 landed; 1,2 in flight
    __builtin_amdgcn_s_barrier();

    const int fr = lane & 15;
    const int kqs = ((lane >> 4) ^ ((lane >> 1) & 3)) * 8;   // swizzled k-chunk

    for (int j = 0; j < NT; ++j) {
        const bf16_t* bufA = lds + (j & 3) * 16384;
        const bf16_t* bufB = bufA + 8192;

        // issue next-tile staging first (full tile of compute hides HBM latency)
        const int jt = j + 3;
        if (jt < NT) {
            const bf16_t *sA, *sB; long long k0;
            tsrc(jt, sA, sB, k0);
            bf16_t* db = lds + (jt & 3) * 16384;
            gload_lds16(sA + aoff0 + k0, db + t * 8);
            gload_lds16(sA + aoff1 + k0, db + 4096 + t * 8);
            gload_lds16(sB + boff0 + k0, db + 8192 + t * 8);
            gload_lds16(sB + boff1 + k0, db + 12288 + t * 8);
        }

        // all 12 fragment reads for this tile (compiler interleaves w/ MFMA)
        bf16x8 a[8], b[4];
#pragma unroll
        for (int mi = 0; mi < 8; mi++)
            a[mi] = *(const bf16x8*)&bufA[(wm * 128 + mi * 16 + fr) * 32 + kqs];
#pragma unroll
        for (int ni = 0; ni < 4; ni++)
            b[ni] = *(const bf16x8*)&bufB[(wn * 64 + ni * 16 + fr) * 32 + kqs];

        __builtin_amdgcn_s_setprio(1);
#pragma unroll
        for (int mi = 0; mi < 8; mi++)
#pragma unroll
            for (int ni = 0; ni < 4; ni++)
                acc[mi][ni] = mfma_bf16(a[mi], b[ni], acc[mi][ni]);
        __builtin_amdgcn_s_setprio(0);

        // single sync point per tile: counted wait (j+1 landed; j+2,j+3 fly)
        if (j + 1 < NT) {
            if (j < NT - 3)       asm volatile("s_waitcnt vmcnt(8)" ::: "memory");
            else if (j == NT - 3) asm volatile("s_waitcnt vmcnt(4)" ::: "memory");
            else                  asm volatile("s_waitcnt vmcnt(0)" ::: "memory");
            __builtin_amdgcn_s_barrier();
        }
    }

    // epilogue: C/D layout col = lane&15, row = (lane>>4)*4 + reg
    const int fc = lane & 15;
    const int fr4 = (lane >> 4) * 4;
#pragma unroll
    for (int mi = 0; mi < 8; mi++)
#pragma unroll
        for (int ni = 0; ni < 4; ni++)
#pragma unroll
            for (int rg = 0; rg < 4; rg++) {
                const int row = rowBase + wm * 128 + mi * 16 + fr4 + rg;
                const int col = colBase + wn * 64 + ni * 16 + fc;
                float v = acc[mi][ni][rg];
                if (BIAS == 1) v += bias[col];
                else if (BIAS == 2) v += bias[row];
                const long long off = (long long)bz * strideC + (long long)row * ldc + col;
                if (OUTMODE == 0) {
                    ((float*)C0)[off] = v;
                } else if (OUTMODE == 1) {
                    ((bf16_t*)C0)[off] = (bf16_t)v;
                } else {
                    const bf16_t h = (bf16_t)v;
                    ((bf16_t*)C0)[off] = h;
                    ((bf16_t*)C1)[off] = (bf16_t)(v - (float)h);
                }
            }
}

// fp32 -> (hi, lo) bf16 split; n multiple of 1024; grid = n/1024 blocks of 256.
__global__ __launch_bounds__(256) void split_f32(const float* __restrict__ x,
                                                 bf16_t* __restrict__ h,
                                                 bf16_t* __restrict__ l)
{
    const long long i = ((long long)blockIdx.x * 256 + threadIdx.x) * 4;
    const float4 v = *(const float4*)&x[i];
    bf16_t hh[4], ll[4];
    const float vv[4] = {v.x, v.y, v.z, v.w};
#pragma unroll
    for (int j = 0; j < 4; j++) {
        hh[j] = (bf16_t)vv[j];
        ll[j] = (bf16_t)(vv[j] - (float)hh[j]);
    }
    *(short4*)&h[i] = *(short4*)hh;
    *(short4*)&l[i] = *(short4*)ll;
}

// fp32 -> bf16 cast; n multiple of 1024; grid = n/1024.
__global__ __launch_bounds__(256) void cast_f32(const float* __restrict__ x,
                                                bf16_t* __restrict__ y)
{
    const long long i = ((long long)blockIdx.x * 256 + threadIdx.x) * 4;
    const float4 v = *(const float4*)&x[i];
    bf16_t hh[4] = {(bf16_t)v.x, (bf16_t)v.y, (bf16_t)v.z, (bf16_t)v.w};
    *(short4*)&y[i] = *(short4*)hh;
}

// Row softmax with mask; S fp32 [rows][2048] -> P bf16 [rows][2048].
// mask row = n0 + (r & 2047).
__global__ __launch_bounds__(256) void softmax_rows(const float* __restrict__ S,
                                                    bf16_t* __restrict__ P,
                                                    const int* __restrict__ mask,
                                                    int n0)
{
    __shared__ float red[4];
    const long long r = blockIdx.x;
    const float* row = S + r * 2048;
    const int* mrow = mask + (long long)(n0 + (int)(r & 2047)) * 2048;
    const int t = threadIdx.x;

    float v[8];
#pragma unroll
    for (int i = 0; i < 8; i++) {
        const int j = i * 256 + t;
        v[i] = (mrow[j] != 0) ? row[j] : -1000000000.0f;
    }
    float m = v[0];
#pragma unroll
    for (int i = 1; i < 8; i++) m = fmaxf(m, v[i]);
#pragma unroll
    for (int off = 32; off; off >>= 1) m = fmaxf(m, __shfl_xor(m, off));
    if ((t & 63) == 0) red[t >> 6] = m;
    __syncthreads();
    const float rowmax = fmaxf(fmaxf(red[0], red[1]), fmaxf(red[2], red[3]));
    __syncthreads();

    float sum = 0.0f;
    float e[8];
#pragma unroll
    for (int i = 0; i < 8; i++) { e[i] = __expf(v[i] - rowmax); sum += e[i]; }
#pragma unroll
    for (int off = 32; off; off >>= 1) sum += __shfl_xor(sum, off);
    if ((t & 63) == 0) red[t >> 6] = sum;
    __syncthreads();
    const float inv = 1.0f / (red[0] + red[1] + red[2] + red[3]);

    bf16_t* prow = P + r * 2048;
#pragma unroll
    for (int i = 0; i < 8; i++) prow[i * 256 + t] = (bf16_t)(e[i] * inv);
}

extern "C" void kernel_launch(void* const* d_in, const int* in_sizes, int n_in,
                              void* d_out, int out_size, void* d_ws, size_t ws_size,
                              hipStream_t stream) {
    constexpr int Bb = 8, N = 2048, M = 2048, D = 1024;
    constexpr long long MB = 1LL << 20;

    const float* querys = (const float*)d_in[0];
    const float* keys   = (const float*)d_in[1];
    const float* values = (const float*)d_in[2];
    const int*   mask   = (const int*)d_in[3];
    const float* Wq = (const float*)d_in[4];
    const float* bq = (const float*)d_in[5];
    const float* Wk = (const float*)d_in[6];
    const float* bk = (const float*)d_in[7];
    const float* Wv = (const float*)d_in[8];
    const float* bv = (const float*)d_in[9];
    float* out = (float*)d_out;

    // ---- adaptive plan ----
    const long long w = (long long)ws_size;
    auto needB = [&](long long cb) { return 10 * MB + cb * 52 * MB; };
    int CB = 0;
    if      (w >= needB(8)) CB = 8;
    else if (w >= needB(4)) CB = 4;
    else if (w >= needB(2)) CB = 2;
    else if (w >= needB(1)) CB = 1;
    const bool batched = (CB != 0);
    int NCH = N;
    if (!batched) {
        CB = 1;
        NCH = (w >= 38 * MB + 512 * 2048 * 6) ? 512 : 256;
    }

    char* ws = (char*)d_ws;
    long long o = 0;
    auto carve = [&](long long bytes) { char* p = ws + o; o += bytes; return p; };
    bf16_t* WqH = (bf16_t*)carve(2 * MB);
    bf16_t* WqL = (bf16_t*)carve(2 * MB);
    bf16_t* WkH = (bf16_t*)carve(2 * MB);
    bf16_t* WkL = (bf16_t*)carve(2 * MB);
    bf16_t* WvB = (bf16_t*)carve(2 * MB);
    bf16_t* XH  = (bf16_t*)carve((long long)CB * 4 * MB);  // also reused as V staging
    bf16_t* XL  = (bf16_t*)carve((long long)CB * 4 * MB);
    bf16_t* QH  = (bf16_t*)carve((long long)CB * 4 * MB);
    bf16_t* QL  = (bf16_t*)carve((long long)CB * 4 * MB);
    bf16_t* KH  = (bf16_t*)carve((long long)CB * 4 * MB);
    bf16_t* KL  = (bf16_t*)carve((long long)CB * 4 * MB);
    bf16_t* VT  = (bf16_t*)carve((long long)CB * 4 * MB);  // [CB][D][M]
    float*  S   = (float*)carve(batched ? (long long)CB * N * M * 4 : (long long)NCH * 2048 * 4);
    bf16_t* P   = (bf16_t*)carve(batched ? (long long)CB * N * M * 2 : (long long)NCH * 2048 * 2);

    dim3 blk(256), blkG(512);
    const long long grpElems = (long long)CB * N * D;

    // weight conversions (once)
    split_f32<<<dim3((D * D) / 1024), blk, 0, stream>>>(Wq, WqH, WqL);
    split_f32<<<dim3((D * D) / 1024), blk, 0, stream>>>(Wk, WkH, WkL);
    cast_f32<<<dim3((D * D) / 1024), blk, 0, stream>>>(Wv, WvB);

    for (int b0 = 0; b0 < Bb; b0 += CB) {
        const long long xoff = (long long)b0 * N * D;
        // q = xq @ Wq^T + bq -> split (rows = CB*N)
        split_f32<<<dim3(grpElems / 1024), blk, 0, stream>>>(querys + xoff, XH, XL);
        gemm256<true, 1, 2><<<dim3(D / 256, CB * N / 256, 1), blkG, 0, stream>>>(
            XH, XL, 0, D, WqH, WqL, 0, D, QH, QL, 0, D, bq, D);
        // k = xk @ Wk^T + bk -> split
        split_f32<<<dim3(grpElems / 1024), blk, 0, stream>>>(keys + xoff, XH, XL);
        gemm256<true, 1, 2><<<dim3(D / 256, CB * M / 256, 1), blkG, 0, stream>>>(
            XH, XL, 0, D, WkH, WkL, 0, D, KH, KL, 0, D, bk, D);
        // vT[z][d][m] = sum_e Wv[d][e]*xv[z][m][e] + bv[d]  (XH = V staging)
        cast_f32<<<dim3(grpElems / 1024), blk, 0, stream>>>(values + xoff, XH);
        gemm256<false, 2, 1><<<dim3(M / 256, D / 256, CB), blkG, 0, stream>>>(
            WvB, nullptr, 0, D, XH, nullptr, (long long)M * D, D,
            VT, nullptr, (long long)D * M, M, bv, D);

        if (batched) {
            // S[z][n][m] = q[z][n] . k[z][m]  (fp32, split)
            gemm256<true, 0, 0><<<dim3(M / 256, N / 256, CB), blkG, 0, stream>>>(
                QH, QL, (long long)N * D, D,
                KH, KL, (long long)M * D, D,
                S, nullptr, (long long)N * M, M, nullptr, D);
            softmax_rows<<<dim3(CB * N), blk, 0, stream>>>(S, P, mask, 0);
            // out[z][n][d] = sum_m P[z][n][m] * vT[z][d][m]
            gemm256<false, 0, 0><<<dim3(D / 256, N / 256, CB), blkG, 0, stream>>>(
                P, nullptr, (long long)N * M, M,
                VT, nullptr, (long long)D * M, M,
                out + xoff, nullptr, (long long)N * D, D, nullptr, M);
        } else {
            for (int z = 0; z < CB; z++) {
                for (int n0 = 0; n0 < N; n0 += NCH) {
                    gemm256<true, 0, 0><<<dim3(M / 256, NCH / 256, 1), blkG, 0, stream>>>(
                        QH + ((long long)z * N + n0) * D, QL + ((long long)z * N + n0) * D, 0, D,
                        KH + (long long)z * M * D, KL + (long long)z * M * D, 0, D,
                        S, nullptr, 0, M, nullptr, D);
                    softmax_rows<<<dim3(NCH), blk, 0, stream>>>(S, P, mask, n0);
                    gemm256<false, 0, 0><<<dim3(D / 256, NCH / 256, 1), blkG, 0, stream>>>(
                        P, nullptr, 0, M, VT + (long long)z * D * M, nullptr, 0, M,
                        out + ((long long)(b0 + z) * N + n0) * D, nullptr, 0, D, nullptr, M);
                }
            }
        }
    }
    (void)in_sizes; (void)n_in; (void)out_size;
}